// Round 13
// baseline (38.408 us; speedup 1.0000x reference)
//
#include <hip/hip_runtime.h>
#include <hip/hip_bf16.h>

// HalfKP input layer, king-grouped MFMA with LDS-staged weights:
//   per king k: D = A_k (nc x 672 bf16 0/1) x W_k (672x256 -> bf16)
//   out[b,c] = bias[c] + D[entry(b,0)] + D[entry(b,1)]
// B=1024, K=64, F=640(+row 640), C=256. W is (64,641,256) fp32 = 42 MB.
//
// R13 vs R12: R9-R12 all plateau at ~22us in the mfma kernel despite 2x
// differences in VALU/MFMA work -> the invariant is the W access pattern
// (per-lane dword loads at 1KB stride = 4 split 64B segments per wave-load,
// ~1.4M L1 line transactions + 2x overfetch). Fix: stage the block's whole
// (672x32) W slice into LDS ONCE via fully-coalesced 128B row loads, packed
// bf16-pairs-along-K (one ds_read_b32 = one B-frag u32). MFMA loop then has
// zero global traffic. Also fused the piece-mask ballot in (pieces is
// L2-resident) -> 2 dispatches total. List build / kh-split / D-write
// verbatim R12 (HW-verified, absmax 0.5).

#define F_DIM 640
#define C_DIM 256
#define SLAB_STRIDE (641 * 256)   // floats per king slab
#define NKING 64
#define LCAP 256                  // list capacity per king
#define NC_MAX 64                 // max 64-entry chunks (nent <= 4096)
#define WPAD 33                   // LDS row stride (u32) for [336] k-pair rows

// ws layout (bytes)
#define WS_PART_OFF 0                        // 2*1024*256*4 = 2 MB
#define WS_NEED (2 * 1024 * 256 * 4)

typedef float  f32x4  __attribute__((ext_vector_type(4)));
typedef short  bf16x8 __attribute__((ext_vector_type(8)));

__device__ __forceinline__ unsigned f2bf_pk(float a, float b) {
    // two RNE fp32->bf16, packed lo|hi (bit-exact, HW-verified R8-R12)
    union { float f; unsigned u; } x, y;
    x.f = a; y.f = b;
    const unsigned ra = (x.u + 0x7FFFu + ((x.u >> 16) & 1u)) >> 16;
    const unsigned rb = (y.u + 0x7FFFu + ((y.u >> 16) & 1u)) >> 16;
    return (ra & 0xFFFFu) | (rb << 16);
}

__device__ __forceinline__ bf16x8 mk_a8(unsigned m32, int g) {
    // A-frag: 8 bf16 0/1 from byte g of a 32-bit window mask (k = g*8 + j)
    const unsigned by = (m32 >> (g * 8)) & 0xFFu;
    union { unsigned u[4]; bf16x8 v; } r;
    #pragma unroll
    for (int i = 0; i < 4; ++i)
        r.u[i] = (((by >> (2 * i)) & 1u) ? 0x3F80u : 0u) |
                 (((by >> (2 * i + 1)) & 1u) ? 0x3F800000u : 0u);
    return r.v;
}

__global__ __launch_bounds__(512, 4)
void halfkp_mfma(const float* __restrict__ W,        // (64,641,256)
                 const int* __restrict__ pieces,     // (B,640) int32 0/1
                 const int* __restrict__ kings,      // flat (B*2)
                 float* __restrict__ partial,        // (2,B,256)
                 int nent)
{
    const int k  = blockIdx.x;
    const int cq = blockIdx.y;               // 0..7, 32 cols each
    const int t  = threadIdx.x;
    const int wv = t >> 6, lane = t & 63;
    const int mt  = wv & 1;                  // M-tile 0..1
    const int ntc = (wv >> 1) & 1;           // N-half 0..1
    const int kh  = wv >> 2;                 // K-half 0..1
    const int li = lane & 15, g = lane >> 4;
    const int colL = ntc * 16 + li;          // col within the 32-col slice
    const int colG = cq * 32 + colL;

    __shared__ unsigned s_W[336 * WPAD];     // 44.4 KB: bf16-pair (2k-rows) x 32 cols
    __shared__ int s_ent[LCAP];
    __shared__ int s_cb[NC_MAX + 1];
    __shared__ unsigned s_m32[32][21];       // per-row window masks
    __shared__ f32x4 s_red[4][64];           // pairwise K-reduce
    __shared__ int s_nk;

    // ---- in-block list build (R10-verified): stable compaction ----
    {
        const int NC = nent >> 6;            // 64-entry chunks
        const int nit = NC >> 3;             // chunks per wave (8 waves)
        unsigned long long mm[8];
        #pragma unroll
        for (int it = 0; it < 8; ++it) {
            if (it < nit) {
                const int c = wv + (it << 3);
                const int kk = kings[(c << 6) + lane];
                mm[it] = __ballot(kk == k);
                if (lane == 0) s_cb[c] = (int)__popcll(mm[it]);
            }
        }
        __syncthreads();
        if (t == 0) {
            int s = 0;
            for (int c = 0; c < NC; ++c) { const int v = s_cb[c]; s_cb[c] = s; s += v; }
            s_nk = min(s, LCAP);
        }
        __syncthreads();
        const unsigned long long lt = (1ull << lane) - 1ull;
        #pragma unroll
        for (int it = 0; it < 8; ++it) {
            if (it < nit) {
                const int c = wv + (it << 3);
                if ((mm[it] >> lane) & 1ull) {
                    const int pos = s_cb[c] + (int)__popcll(mm[it] & lt);
                    if (pos < LCAP) s_ent[pos] = (c << 6) + lane;
                }
            }
        }
        __syncthreads();
    }
    const int n_k = s_nk;

    // ---- stage W slice to LDS once (coalesced 128B row segments) ----
    // s_W[fp*WPAD + c] = bf16(W[2fp][cq*32+c]) | bf16(W[2fp+1][..]) << 16
    {
        const float* __restrict__ Wq = W + (size_t)k * SLAB_STRIDE + cq * 32;
        const int c = t & 31;
        const int r0 = t >> 5;               // 0..15
        #pragma unroll 3
        for (int it = 0; it < 21; ++it) {
            const int fp = it * 16 + r0;     // 0..335
            const int fe = min(2 * fp, F_DIM);
            const int fo = min(2 * fp + 1, F_DIM);
            const float we = Wq[(size_t)fe * C_DIM + c];
            const float wo = Wq[(size_t)fo * C_DIM + c];
            s_W[fp * WPAD + c] = f2bf_pk(we, wo);
        }
    }
    // (barrier below, at first chunk's mask sync, covers staging too)

    for (int mb = 0; mb < n_k; mb += 32) {
        const int nc = min(n_k - mb, 32);

        // ---- per-chunk piece masks via direct ballot (pieces L2-resident) ----
        #pragma unroll
        for (int j = 0; j < 4; ++j) {
            const int r = wv + 8 * j;        // 0..31, wave-uniform row
            const int id = (r < nc) ? s_ent[mb + r] : -1;
            if (id >= 0) {
                const int* __restrict__ pb = pieces + (size_t)(id >> 1) * F_DIM;
                #pragma unroll 2
                for (int w2 = 0; w2 < 10; ++w2) {
                    const unsigned long long m64 = __ballot(pb[w2 * 64 + lane] != 0);
                    if (lane == 0) {
                        s_m32[r][2 * w2]     = (unsigned)m64;
                        s_m32[r][2 * w2 + 1] = (unsigned)(m64 >> 32);
                    }
                }
                if (lane == 0) s_m32[r][20] = 1u;   // always-active row 640
            } else {
                if (lane < 21) s_m32[r][lane] = 0u;
            }
        }
        __syncthreads();

        // ---- MFMA over this wave's K-half; B-frags from LDS ----
        const unsigned* mrow = s_m32[mt * 16 + li];
        f32x4 acc = {0.f, 0.f, 0.f, 0.f};
        {
            const int ks_beg = kh ? 10 : 0;
            const int ks_end = kh ? 21 : 10;
            #pragma unroll 2
            for (int ks = ks_beg; ks < ks_end; ++ks) {
                const unsigned* bp = &s_W[(ks * 16 + g * 4) * WPAD + colL];
                union { unsigned u[4]; bf16x8 v; } bb;
                #pragma unroll
                for (int jj = 0; jj < 4; ++jj)
                    bb.u[jj] = bp[jj * WPAD];
                const bf16x8 af = mk_a8(mrow[ks], g);
                acc = __builtin_amdgcn_mfma_f32_16x16x32_bf16(af, bb.v, acc, 0, 0, 0);
            }
        }
        if (kh == 1) s_red[wv & 3][lane] = acc;      // publish K-half 1
        __syncthreads();
        if (kh == 0) {
            acc += s_red[wv & 3][lane];              // partner (mt,ntc) wave
            // D: reg i -> row = mt*16 + 4*g + i, col = colG (m89-verified)
            #pragma unroll
            for (int i = 0; i < 4; ++i) {
                const int row = mt * 16 + 4 * g + i;
                if (row < nc) {
                    const int id = s_ent[mb + row];
                    partial[(((size_t)(id & 1)) * 1024 + (id >> 1)) * C_DIM + colG] = acc[i];
                }
            }
        }
        __syncthreads();   // protect s_m32/s_red before next chunk
    }
}

__global__ __launch_bounds__(256)
void finalize(const float* __restrict__ partial,
              const float* __restrict__ bias,
              float* __restrict__ out)
{
    const int i = blockIdx.x * 256 + threadIdx.x;    // float4 index, B*64 total
    const float4 b4 = ((const float4*)bias)[i & 63];
    const float4 p0 = ((const float4*)partial)[i];
    const float4 p1 = ((const float4*)partial)[1024 * 64 + i];
    float4 o;
    o.x = b4.x + p0.x + p1.x;
    o.y = b4.y + p0.y + p1.y;
    o.z = b4.z + p0.z + p1.z;
    o.w = b4.w + p0.w + p1.w;
    ((float4*)out)[i] = o;
}

// ---- fallback (R3 path) if ws is too small ----
__global__ __launch_bounds__(256)
void halfkp_fallback(const int* __restrict__ pieces, const int* __restrict__ kings,
                     const float* __restrict__ W, const float* __restrict__ bias,
                     float* __restrict__ out)
{
    const int b = blockIdx.x;
    const int c = threadIdx.x;
    const int lane = c & 63;
    const int k0 = kings[2 * b + 0];
    const int k1 = kings[2 * b + 1];
    const float* W0 = W + (size_t)k0 * SLAB_STRIDE + c;
    const float* W1 = W + (size_t)k1 * SLAB_STRIDE + c;
    float acc = bias[c] + W0[640 * 256] + W1[640 * 256];
    const int* pi = pieces + (size_t)b * F_DIM;
    #pragma unroll
    for (int ch = 0; ch < 10; ++ch) {
        int v = pi[ch * 64 + lane];
        unsigned long long m = __ballot(v != 0);
        const float* b0 = W0 + ch * 64 * 256;
        const float* b1 = W1 + ch * 64 * 256;
        while (m) {
            const int f = __builtin_ctzll(m);
            m &= m - 1;
            acc += b0[f * 256] + b1[f * 256];
        }
    }
    out[(size_t)b * C_DIM + c] = acc;
}

extern "C" void kernel_launch(void* const* d_in, const int* in_sizes, int n_in,
                              void* d_out, int out_size, void* d_ws, size_t ws_size,
                              hipStream_t stream) {
    const int* pieces = (const int*)d_in[0];   // (1024, 640) int32 bools
    const int* kings  = (const int*)d_in[1];   // (1024, 2) int32
    const float* W    = (const float*)d_in[2]; // (64, 641, 256) f32
    const float* bias = (const float*)d_in[3]; // (256,) f32
    float* out        = (float*)d_out;         // (1024, 256) f32

    const int B = in_sizes[1] / 2;             // 1024
    const int nent = 2 * B;

    if (ws_size < (size_t)WS_NEED) {
        halfkp_fallback<<<dim3(B), dim3(C_DIM), 0, stream>>>(pieces, kings, W, bias, out);
        return;
    }

    float* part = (float*)((char*)d_ws + WS_PART_OFF);

    halfkp_mfma<<<dim3(NKING, 8), dim3(512), 0, stream>>>(W, pieces, kings, part, nent);
    finalize<<<dim3(B * 64 / 256), dim3(256), 0, stream>>>(part, bias, out);
}

// Round 14
// 26.718 us; speedup vs baseline: 1.4375x; 1.4375x over previous
//
#include <hip/hip_runtime.h>
#include <hip/hip_bf16.h>

// HalfKP input layer, king-grouped MFMA with LDS-staged weights (v2):
//   per king k: D = A_k (nc x 672 bf16 0/1) x W_k (672x256 -> bf16)
//   out[b,c] = bias[c] + D[entry(b,0)] + D[entry(b,1)]
// B=1024, K=64, F=640(+row 640), C=256. W is (64,641,256) fp32 = 42 MB.
//
// R14 vs R13: R13's staging loaded scalar dwords and packed immediately ->
// waitcnt drained the queue, ~2 loads in flight, 637 GB/s (counter-proven).
// Staging v2: task=(fp,c4): TWO independent float4 loads (rows 2fp,2fp+1),
// pack in regs, ONE ds_write_b128; unroll 3 -> 96B in flight/lane -> memory-
// ceiling staging. WPAD 36 (144B rows, 16B-aligned, reads <=2-way = free).
// Mask path restored to R12's packed-u64-in-ws (pack_masks kernel) - the
// R13 ballot-chain was 40 serialized L2 loads/wave/chunk. Window 20 joins
// the uniform LDS path (clamped row 641->640 masked by A-bit=0, bit-exact).
// List build / kh-split / reduce / D-write verbatim R12 (absmax 0.5).

#define F_DIM 640
#define C_DIM 256
#define SLAB_STRIDE (641 * 256)   // floats per king slab
#define NKING 64
#define LCAP 256                  // list capacity per king
#define NC_MAX 64                 // max 64-entry chunks (nent <= 4096)
#define WPAD 36                   // LDS row stride in u32 (144B, 16B-aligned)

// ws layout (bytes)
#define WS_MASK_OFF 0                        // 1024*10*8 = 80 KB
#define WS_PART_OFF 81920                    // 2*1024*256*4 = 2 MB
#define WS_NEED (WS_PART_OFF + 2 * 1024 * 256 * 4)

typedef float  f32x4  __attribute__((ext_vector_type(4)));
typedef short  bf16x8 __attribute__((ext_vector_type(8)));

__device__ __forceinline__ unsigned f2bf_pk(float a, float b) {
    // two RNE fp32->bf16, packed lo|hi (bit-exact, HW-verified R8-R13)
    union { float f; unsigned u; } x, y;
    x.f = a; y.f = b;
    const unsigned ra = (x.u + 0x7FFFu + ((x.u >> 16) & 1u)) >> 16;
    const unsigned rb = (y.u + 0x7FFFu + ((y.u >> 16) & 1u)) >> 16;
    return (ra & 0xFFFFu) | (rb << 16);
}

__device__ __forceinline__ bf16x8 mk_a8(unsigned m32, int g) {
    // A-frag: 8 bf16 0/1 from byte g of a 32-bit window mask (k = g*8 + j)
    const unsigned by = (m32 >> (g * 8)) & 0xFFu;
    union { unsigned u[4]; bf16x8 v; } r;
    #pragma unroll
    for (int i = 0; i < 4; ++i)
        r.u[i] = (((by >> (2 * i)) & 1u) ? 0x3F80u : 0u) |
                 (((by >> (2 * i + 1)) & 1u) ? 0x3F800000u : 0u);
    return r.v;
}

__global__ __launch_bounds__(256)
void pack_masks(const int* __restrict__ pieces,          // (B,640) int32 0/1
                unsigned long long* __restrict__ mask,   // (B,10)
                int nwords)                              // B*10
{
    const int gw = blockIdx.x * 4 + (threadIdx.x >> 6);
    const int lane = threadIdx.x & 63;
    if (gw >= nwords) return;
    const int v = pieces[(size_t)gw * 64 + lane];
    const unsigned long long m = __ballot(v != 0);
    if (lane == 0) mask[gw] = m;
}

__global__ __launch_bounds__(512, 4)
void halfkp_mfma(const float* __restrict__ W,                 // (64,641,256)
                 const unsigned long long* __restrict__ mask, // (B,10)
                 const int* __restrict__ kings,               // flat (B*2)
                 float* __restrict__ partial,                 // (2,B,256)
                 int nent)
{
    const int k  = blockIdx.x;
    const int cq = blockIdx.y;               // 0..7, 32 cols each
    const int t  = threadIdx.x;
    const int wv = t >> 6, lane = t & 63;
    const int mt  = wv & 1;                  // M-tile 0..1
    const int ntc = (wv >> 1) & 1;           // N-half 0..1
    const int kh  = wv >> 2;                 // K-half 0..1
    const int li = lane & 15, g = lane >> 4;
    const int colL = ntc * 16 + li;
    const int colG = cq * 32 + colL;

    __shared__ unsigned s_W[336 * WPAD];     // 48.4 KB bf16-pair x 32 cols
    __shared__ int s_ent[LCAP];
    __shared__ int s_cb[NC_MAX + 1];
    __shared__ unsigned s_m32[32][21];       // per-row window masks
    __shared__ f32x4 s_red[4][64];           // pairwise K-reduce
    __shared__ int s_nk;

    // ---- in-block list build (R10-verified): stable compaction ----
    {
        const int NC = nent >> 6;            // 64-entry chunks
        const int nit = NC >> 3;             // chunks per wave (8 waves)
        unsigned long long mm[8];
        #pragma unroll
        for (int it = 0; it < 8; ++it) {
            if (it < nit) {
                const int c = wv + (it << 3);
                const int kk = kings[(c << 6) + lane];
                mm[it] = __ballot(kk == k);
                if (lane == 0) s_cb[c] = (int)__popcll(mm[it]);
            }
        }
        __syncthreads();
        if (t == 0) {
            int s = 0;
            for (int c = 0; c < NC; ++c) { const int v = s_cb[c]; s_cb[c] = s; s += v; }
            s_nk = min(s, LCAP);
        }
        __syncthreads();
        const unsigned long long lt = (1ull << lane) - 1ull;
        #pragma unroll
        for (int it = 0; it < 8; ++it) {
            if (it < nit) {
                const int c = wv + (it << 3);
                if ((mm[it] >> lane) & 1ull) {
                    const int pos = s_cb[c] + (int)__popcll(mm[it] & lt);
                    if (pos < LCAP) s_ent[pos] = (c << 6) + lane;
                }
            }
        }
    }

    // ---- stage W slice to LDS once: float4 pairs -> pack -> ds_write_b128 ----
    // task = fp*8 + c4 (fp<336 row-pair, c4<8 col-quad). 2688 tasks.
    {
        const float* __restrict__ Wq = W + (size_t)k * SLAB_STRIDE + cq * 32;
        #pragma unroll 3
        for (int i = 0; i < 6; ++i) {
            const int task = t + (i << 9);
            if (task < 336 * 8) {
                const int fp = task >> 3, c4 = task & 7;
                const int fe = min(2 * fp, F_DIM);
                const int fo = min(2 * fp + 1, F_DIM);
                const float4 e = *(const float4*)&Wq[(size_t)fe * C_DIM + c4 * 4];
                const float4 o = *(const float4*)&Wq[(size_t)fo * C_DIM + c4 * 4];
                union { unsigned u[4]; f32x4 v; } pk;
                pk.u[0] = f2bf_pk(e.x, o.x);
                pk.u[1] = f2bf_pk(e.y, o.y);
                pk.u[2] = f2bf_pk(e.z, o.z);
                pk.u[3] = f2bf_pk(e.w, o.w);
                *(f32x4*)&s_W[fp * WPAD + c4 * 4] = pk.v;
            }
        }
    }
    __syncthreads();
    const int n_k = s_nk;

    for (int mb = 0; mb < n_k; mb += 32) {
        const int nc = min(n_k - mb, 32);

        // ---- per-chunk mask fill from packed ws masks (R12-verified) ----
        for (int idx = t; idx < 32 * 21; idx += 512) {
            const int row = idx & 31, ks = idx >> 5;
            const int id = (row < nc) ? s_ent[mb + row] : -1;
            unsigned v = 0;
            if (id >= 0) {
                if (ks < 20) {
                    const unsigned long long mw = mask[(size_t)(id >> 1) * 10 + (ks >> 1)];
                    v = (unsigned)(mw >> ((ks & 1) * 32));
                } else {
                    v = 1u;                  // always-active row 640
                }
            }
            s_m32[row][ks] = v;
        }
        __syncthreads();

        // ---- MFMA over this wave's K-half; B-frags from LDS ----
        const unsigned* mrow = s_m32[mt * 16 + li];
        f32x4 acc = {0.f, 0.f, 0.f, 0.f};
        {
            const int ks_beg = kh ? 10 : 0;
            const int ks_end = kh ? 21 : 10;
            #pragma unroll 2
            for (int ks = ks_beg; ks < ks_end; ++ks) {
                const unsigned* bp = &s_W[(ks * 16 + g * 4) * WPAD + colL];
                union { unsigned u[4]; bf16x8 v; } bb;
                #pragma unroll
                for (int jj = 0; jj < 4; ++jj)
                    bb.u[jj] = bp[jj * WPAD];
                const bf16x8 af = mk_a8(mrow[ks], g);
                acc = __builtin_amdgcn_mfma_f32_16x16x32_bf16(af, bb.v, acc, 0, 0, 0);
            }
        }
        if (kh == 1) s_red[wv & 3][lane] = acc;      // publish K-half 1
        __syncthreads();
        if (kh == 0) {
            acc += s_red[wv & 3][lane];              // partner (mt,ntc) wave
            // D: reg i -> row = mt*16 + 4*g + i, col = colG (m89-verified)
            #pragma unroll
            for (int i = 0; i < 4; ++i) {
                const int row = mt * 16 + 4 * g + i;
                if (row < nc) {
                    const int id = s_ent[mb + row];
                    partial[(((size_t)(id & 1)) * 1024 + (id >> 1)) * C_DIM + colG] = acc[i];
                }
            }
        }
        __syncthreads();   // protect s_m32/s_red before next chunk
    }
}

__global__ __launch_bounds__(256)
void finalize(const float* __restrict__ partial,
              const float* __restrict__ bias,
              float* __restrict__ out)
{
    const int i = blockIdx.x * 256 + threadIdx.x;    // float4 index, B*64 total
    const float4 b4 = ((const float4*)bias)[i & 63];
    const float4 p0 = ((const float4*)partial)[i];
    const float4 p1 = ((const float4*)partial)[1024 * 64 + i];
    float4 o;
    o.x = b4.x + p0.x + p1.x;
    o.y = b4.y + p0.y + p1.y;
    o.z = b4.z + p0.z + p1.z;
    o.w = b4.w + p0.w + p1.w;
    ((float4*)out)[i] = o;
}

// ---- fallback (R3 path) if ws is too small ----
__global__ __launch_bounds__(256)
void halfkp_fallback(const int* __restrict__ pieces, const int* __restrict__ kings,
                     const float* __restrict__ W, const float* __restrict__ bias,
                     float* __restrict__ out)
{
    const int b = blockIdx.x;
    const int c = threadIdx.x;
    const int lane = c & 63;
    const int k0 = kings[2 * b + 0];
    const int k1 = kings[2 * b + 1];
    const float* W0 = W + (size_t)k0 * SLAB_STRIDE + c;
    const float* W1 = W + (size_t)k1 * SLAB_STRIDE + c;
    float acc = bias[c] + W0[640 * 256] + W1[640 * 256];
    const int* pi = pieces + (size_t)b * F_DIM;
    #pragma unroll
    for (int ch = 0; ch < 10; ++ch) {
        int v = pi[ch * 64 + lane];
        unsigned long long m = __ballot(v != 0);
        const float* b0 = W0 + ch * 64 * 256;
        const float* b1 = W1 + ch * 64 * 256;
        while (m) {
            const int f = __builtin_ctzll(m);
            m &= m - 1;
            acc += b0[f * 256] + b1[f * 256];
        }
    }
    out[(size_t)b * C_DIM + c] = acc;
}

extern "C" void kernel_launch(void* const* d_in, const int* in_sizes, int n_in,
                              void* d_out, int out_size, void* d_ws, size_t ws_size,
                              hipStream_t stream) {
    const int* pieces = (const int*)d_in[0];   // (1024, 640) int32 bools
    const int* kings  = (const int*)d_in[1];   // (1024, 2) int32
    const float* W    = (const float*)d_in[2]; // (64, 641, 256) f32
    const float* bias = (const float*)d_in[3]; // (256,) f32
    float* out        = (float*)d_out;         // (1024, 256) f32

    const int B = in_sizes[1] / 2;             // 1024
    const int nent = 2 * B;
    const int nwords = B * 10;

    if (ws_size < (size_t)WS_NEED) {
        halfkp_fallback<<<dim3(B), dim3(C_DIM), 0, stream>>>(pieces, kings, W, bias, out);
        return;
    }

    unsigned long long* mask = (unsigned long long*)((char*)d_ws + WS_MASK_OFF);
    float* part = (float*)((char*)d_ws + WS_PART_OFF);

    pack_masks<<<dim3((nwords + 3) / 4), dim3(256), 0, stream>>>(pieces, mask, nwords);
    halfkp_mfma<<<dim3(NKING, 8), dim3(512), 0, stream>>>(W, mask, kings, part, nent);
    finalize<<<dim3(B * 64 / 256), dim3(256), 0, stream>>>(part, bias, out);
}